// Round 1
// baseline (4511.361 us; speedup 1.0000x reference)
//
#include <hip/hip_runtime.h>
#include <math.h>

#define NFULL 2177   // 1 + L + S
#define NN    2176   // minor size (NFULL-1), = 34*64
#define NB    64
#define NMAT  8      // 4 batches x {z, target}
#define NBATCH 4

// ---------------- build phase ----------------

__global__ void init_cs_kernel(float* __restrict__ cs) {
  int i = blockIdx.x * blockDim.x + threadIdx.x;
  if (i < NMAT * NN) cs[i] = 0.f;
}

// column sums of w for both masks; colsum[j] = sum_i exp(s[i][j])*mask[i][j], i,j < len
__global__ void colsum_kernel(const float* __restrict__ scores,
                              const float* __restrict__ zm,
                              const float* __restrict__ tm,
                              const int* __restrict__ lengths,
                              float* __restrict__ cs) {
  int c = blockIdx.x * blockDim.x + threadIdx.x;  // minor column, node j = c+1
  if (c >= NN) return;
  int rc = blockIdx.y;
  int b  = blockIdx.z;
  int len = lengths[b];
  int j = c + 1;
  if (j >= len) return;  // cs stays 0 (init kernel)
  int i0 = rc * 128;
  int i1 = i0 + 128; if (i1 > len) i1 = len;
  if (i0 >= i1) return;
  size_t base = (size_t)b * NFULL * NFULL + j;
  float az = 0.f, at = 0.f;
  for (int i = i0; i < i1; ++i) {
    size_t off = base + (size_t)i * NFULL;
    float e = __expf(scores[off]);
    az += e * zm[off];
    at += e * tm[off];
  }
  atomicAdd(&cs[b * NN + c], az);
  atomicAdd(&cs[(NBATCH + b) * NN + c], at);
}

// M[r][c] = (r==c ? colsum[c] + pad : 0) - w[r+1][c+1], for both masks
__global__ void build_kernel(const float* __restrict__ scores,
                             const float* __restrict__ zm,
                             const float* __restrict__ tm,
                             const int* __restrict__ lengths,
                             const float* __restrict__ cs,
                             float* __restrict__ M) {
  int c = blockIdx.x * blockDim.x + threadIdx.x;
  if (c >= NN) return;
  int r = blockIdx.y;
  int b = blockIdx.z;
  int len = lengths[b];
  int i = r + 1, j = c + 1;
  float vz = 0.f, vt = 0.f;
  if (i < len && j < len) {
    size_t off = (size_t)b * NFULL * NFULL + (size_t)i * NFULL + j;
    float e = __expf(scores[off]);
    vz = e * zm[off];
    vt = e * tm[off];
  }
  float dz = 0.f, dt = 0.f;
  if (r == c) {
    float pad = (j < len) ? 0.f : 1.f;  // invalid node -> identity row/col
    dz = cs[b * NN + c] + pad;
    dt = cs[(NBATCH + b) * NN + c] + pad;
  }
  size_t mo = (size_t)r * NN + c;
  M[(size_t)b * NN * NN + mo]            = dz - vz;
  M[(size_t)(NBATCH + b) * NN * NN + mo] = dt - vt;
}

// ---------------- blocked LU (no pivoting; matrices are column diag-dominant) ----------------

// factor 64x64 diagonal block in-place (L unit-lower \ U upper)
__global__ __launch_bounds__(256) void factor_diag(float* __restrict__ Mb, int k0) {
  __shared__ float T[64][65];
  int m = blockIdx.x;
  float* A = Mb + (size_t)m * NN * NN;
  int tid = threadIdx.x;
  for (int idx = tid; idx < 64 * 64; idx += 256) {
    int r = idx >> 6, c = idx & 63;
    T[r][c] = A[(size_t)(k0 + r) * NN + (k0 + c)];
  }
  __syncthreads();
  for (int j = 0; j < 63; ++j) {
    float inv = 1.0f / T[j][j];
    for (int r = j + 1 + tid; r < 64; r += 256) T[r][j] *= inv;
    __syncthreads();
    int rem = 63 - j;
    for (int idx = tid; idx < rem * rem; idx += 256) {
      int rr = j + 1 + idx / rem;
      int cc = j + 1 + idx % rem;
      T[rr][cc] -= T[rr][j] * T[j][cc];
    }
    __syncthreads();
  }
  for (int idx = tid; idx < 64 * 64; idx += 256) {
    int r = idx >> 6, c = idx & 63;
    A[(size_t)(k0 + r) * NN + (k0 + c)] = T[r][c];
  }
}

// fused triangular solves: role 0 -> L21 = A21 * U11^-1 (row solves)
//                          role 1 -> U12 = L11^-1 * A12 (col solves)
__global__ __launch_bounds__(64) void panel_solve(float* __restrict__ Mb, int k0) {
  __shared__ float D[64][65];  // factored diagonal block (L\U)
  __shared__ float T[64][65];  // tile being solved
  int m    = blockIdx.y;
  int role = blockIdx.z;
  float* A = Mb + (size_t)m * NN * NN;
  int tid = threadIdx.x;
  int obase = k0 + 64 + blockIdx.x * 64;
  for (int idx = tid; idx < 64 * 64; idx += 64) {
    int r = idx >> 6, c = idx & 63;
    D[r][c] = A[(size_t)(k0 + r) * NN + (k0 + c)];
  }
  if (role == 0) {
    for (int idx = tid; idx < 64 * 64; idx += 64) {
      int r = idx >> 6, c = idx & 63;
      T[r][c] = A[(size_t)(obase + r) * NN + (k0 + c)];
    }
    __syncthreads();
    // row tid: solve l * U11 = a   (each thread owns its row; no cross-thread deps)
    for (int j = 0; j < 64; ++j) {
      float acc = T[tid][j];
      for (int t = 0; t < j; ++t) acc -= T[tid][t] * D[t][j];
      T[tid][j] = acc / D[j][j];
    }
    __syncthreads();
    for (int idx = tid; idx < 64 * 64; idx += 64) {
      int r = idx >> 6, c = idx & 63;
      A[(size_t)(obase + r) * NN + (k0 + c)] = T[r][c];
    }
  } else {
    for (int idx = tid; idx < 64 * 64; idx += 64) {
      int r = idx >> 6, c = idx & 63;
      T[r][c] = A[(size_t)(k0 + r) * NN + (obase + c)];
    }
    __syncthreads();
    // column tid: solve L11 * u = a (unit diag; each thread owns its column)
    int c = tid;
    for (int j = 1; j < 64; ++j) {
      float acc = T[j][c];
      for (int t = 0; t < j; ++t) acc -= D[j][t] * T[t][c];
      T[j][c] = acc;
    }
    __syncthreads();
    for (int idx = tid; idx < 64 * 64; idx += 64) {
      int r = idx >> 6, c = idx & 63;
      A[(size_t)(k0 + r) * NN + (obase + c)] = T[r][c];
    }
  }
}

// trailing update: A22 -= L21 * U12, 64x64 tile per block, 4x4 microtile per thread, K=64
__global__ __launch_bounds__(256) void trail_gemm(float* __restrict__ Mb, int k0) {
  __shared__ float Lt[64][68];  // Lt[k][r]
  __shared__ float Ut[64][68];  // Ut[k][c]
  int m = blockIdx.z;
  float* A = Mb + (size_t)m * NN * NN;
  int base  = k0 + 64;
  int rbase = base + blockIdx.y * 64;
  int cbase = base + blockIdx.x * 64;
  int tid = threadIdx.x;
  for (int idx = tid; idx < 64 * 64; idx += 256) {
    int r = idx >> 6, k = idx & 63;
    Lt[k][r] = A[(size_t)(rbase + r) * NN + (k0 + k)];
  }
  for (int idx = tid; idx < 64 * 64; idx += 256) {
    int k = idx >> 6, c = idx & 63;
    Ut[k][c] = A[(size_t)(k0 + k) * NN + (cbase + c)];
  }
  __syncthreads();
  int c0 = (tid & 15) << 2;   // consecutive lanes -> consecutive columns (coalesced C RMW)
  int r0 = (tid >> 4) << 2;
  float acc[4][4];
#pragma unroll
  for (int i = 0; i < 4; ++i)
#pragma unroll
    for (int jj = 0; jj < 4; ++jj) acc[i][jj] = 0.f;
#pragma unroll 8
  for (int k = 0; k < 64; ++k) {
    float4 a  = *(const float4*)&Lt[k][r0];
    float4 bv = *(const float4*)&Ut[k][c0];
    acc[0][0] += a.x * bv.x; acc[0][1] += a.x * bv.y; acc[0][2] += a.x * bv.z; acc[0][3] += a.x * bv.w;
    acc[1][0] += a.y * bv.x; acc[1][1] += a.y * bv.y; acc[1][2] += a.y * bv.z; acc[1][3] += a.y * bv.w;
    acc[2][0] += a.z * bv.x; acc[2][1] += a.z * bv.y; acc[2][2] += a.z * bv.z; acc[2][3] += a.z * bv.w;
    acc[3][0] += a.w * bv.x; acc[3][1] += a.w * bv.y; acc[3][2] += a.w * bv.z; acc[3][3] += a.w * bv.w;
  }
#pragma unroll
  for (int i = 0; i < 4; ++i) {
    float4* p = (float4*)&A[(size_t)(rbase + r0 + i) * NN + (cbase + c0)];
    float4 v = *p;
    v.x -= acc[i][0]; v.y -= acc[i][1]; v.z -= acc[i][2]; v.w -= acc[i][3];
    *p = v;
  }
}

// ---------------- reduction ----------------

__global__ void logdet_kernel(const float* __restrict__ Mb, double* __restrict__ dlog) {
  int m = blockIdx.x;
  const float* A = Mb + (size_t)m * NN * NN;
  double s = 0.0;
  for (int i = threadIdx.x; i < NN; i += 256)
    s += (double)logf(fabsf(A[(size_t)i * NN + i]));
  __shared__ double red[256];
  red[threadIdx.x] = s;
  __syncthreads();
  for (int k = 128; k > 0; k >>= 1) {
    if (threadIdx.x < k) red[threadIdx.x] += red[threadIdx.x + k];
    __syncthreads();
  }
  if (threadIdx.x == 0) dlog[m] = red[0];
}

__global__ void final_kernel(const double* __restrict__ dlog, float* __restrict__ out) {
  if (threadIdx.x == 0) {
    double acc = 0.0;
    for (int b = 0; b < NBATCH; ++b) acc += dlog[b] - dlog[NBATCH + b];
    out[0] = (float)(acc * 0.25);
  }
}

// ---------------- launch ----------------

extern "C" void kernel_launch(void* const* d_in, const int* in_sizes, int n_in,
                              void* d_out, int out_size, void* d_ws, size_t ws_size,
                              hipStream_t stream) {
  const float* scores  = (const float*)d_in[0];
  const float* tm      = (const float*)d_in[1];  // target_mask
  const float* zm      = (const float*)d_in[2];  // z_mask
  const int*   lengths = (const int*)d_in[3];
  float* out = (float*)d_out;

  // ws layout: M (8 * 2176^2 f32 = 151.5 MB) | cs (8*2176 f32) | dlog (8 f64)
  float* M  = (float*)d_ws;
  float* cs = M + (size_t)NMAT * NN * NN;
  double* dlog = (double*)(cs + (size_t)NMAT * NN);

  init_cs_kernel<<<(NMAT * NN + 255) / 256, 256, 0, stream>>>(cs);
  colsum_kernel<<<dim3((NN + 255) / 256, (NFULL + 127) / 128, NBATCH), 256, 0, stream>>>(
      scores, zm, tm, lengths, cs);
  build_kernel<<<dim3((NN + 255) / 256, NN, NBATCH), 256, 0, stream>>>(
      scores, zm, tm, lengths, cs, M);

  for (int k0 = 0; k0 < NN; k0 += NB) {
    factor_diag<<<NMAT, 256, 0, stream>>>(M, k0);
    int rem = NN - k0 - NB;
    if (rem > 0) {
      panel_solve<<<dim3(rem / 64, NMAT, 2), 64, 0, stream>>>(M, k0);
      trail_gemm<<<dim3(rem / 64, rem / 64, NMAT), 256, 0, stream>>>(M, k0);
    }
  }

  logdet_kernel<<<NMAT, 256, 0, stream>>>(M, dlog);
  final_kernel<<<1, 64, 0, stream>>>(dlog, out);
}